// Round 1
// baseline (218.776 us; speedup 1.0000x reference)
//
#include <hip/hip_runtime.h>
#include <math.h>

#define NLUT 2048

// ---------------------------------------------------------------------------
// Full QCNN evaluation for one scalar input x (the broadcast conv_val).
// Weight pointers may be global or LDS. Layers: 8->16->16->12->8->4->4->1.
// ---------------------------------------------------------------------------
__device__ __forceinline__ float eval_net(
    float x,
    const float* W_fm, const float* b_fm,
    const float* W_c1, const float* b_c1,
    const float* W_p1, const float* b_p1,
    const float* W_c2, const float* b_c2,
    const float* W_p2, const float* b_p2,
    const float* W_c3, const float* b_c3,
    const float* W_h,  const float* b_h)
{
    float h[16], g[16];
    // fm: input is x broadcast to 8 lanes -> x * colsum(W_fm) + b
    #pragma unroll
    for (int j = 0; j < 16; ++j) {
        float a = b_fm[j];
        #pragma unroll
        for (int i = 0; i < 8; ++i) a = fmaf(x, W_fm[i * 16 + j], a);
        h[j] = tanhf(a);
    }
    // c1: 16 -> 16
    #pragma unroll
    for (int j = 0; j < 16; ++j) {
        float a = b_c1[j];
        #pragma unroll
        for (int i = 0; i < 16; ++i) a = fmaf(h[i], W_c1[i * 16 + j], a);
        g[j] = tanhf(a);
    }
    // p1: 16 -> 12
    #pragma unroll
    for (int j = 0; j < 12; ++j) {
        float a = b_p1[j];
        #pragma unroll
        for (int i = 0; i < 16; ++i) a = fmaf(g[i], W_p1[i * 12 + j], a);
        h[j] = tanhf(a);
    }
    // c2: 12 -> 8
    #pragma unroll
    for (int j = 0; j < 8; ++j) {
        float a = b_c2[j];
        #pragma unroll
        for (int i = 0; i < 12; ++i) a = fmaf(h[i], W_c2[i * 8 + j], a);
        g[j] = tanhf(a);
    }
    // p2: 8 -> 4
    #pragma unroll
    for (int j = 0; j < 4; ++j) {
        float a = b_p2[j];
        #pragma unroll
        for (int i = 0; i < 8; ++i) a = fmaf(g[i], W_p2[i * 4 + j], a);
        h[j] = tanhf(a);
    }
    // c3: 4 -> 4
    #pragma unroll
    for (int j = 0; j < 4; ++j) {
        float a = b_c3[j];
        #pragma unroll
        for (int i = 0; i < 4; ++i) a = fmaf(h[i], W_c3[i * 4 + j], a);
        g[j] = tanhf(a);
    }
    // head: 4 -> 1, sigmoid
    float a = b_h[0];
    #pragma unroll
    for (int i = 0; i < 4; ++i) a = fmaf(g[i], W_h[i], a);
    return 1.0f / (1.0f + expf(-a));
}

// ---------------------------------------------------------------------------
// Kernel 1: build LUT of f(conv_val) over conv_val in [0,1].
// lut[i] = { f(i/(N-1)), f((i+1)/(N-1)) - f(i/(N-1)) }  (delta clamped at end)
// ---------------------------------------------------------------------------
__global__ __launch_bounds__(256) void build_lut_kernel(
    const float* __restrict__ W_fm, const float* __restrict__ b_fm,
    const float* __restrict__ W_c1, const float* __restrict__ b_c1,
    const float* __restrict__ W_p1, const float* __restrict__ b_p1,
    const float* __restrict__ W_c2, const float* __restrict__ b_c2,
    const float* __restrict__ W_p2, const float* __restrict__ b_p2,
    const float* __restrict__ W_c3, const float* __restrict__ b_c3,
    const float* __restrict__ W_h,  const float* __restrict__ b_h,
    float2* __restrict__ lut)
{
    // Stage all 785 weight floats into LDS (broadcast reads in eval_net).
    __shared__ float s[785];
    const float* srcs[14] = {W_fm, b_fm, W_c1, b_c1, W_p1, b_p1,
                             W_c2, b_c2, W_p2, b_p2, W_c3, b_c3, W_h, b_h};
    const int offs[15] = {0, 128, 144, 400, 416, 608, 620, 716, 724, 756,
                          760, 776, 780, 784, 785};
    for (int p = 0; p < 14; ++p) {
        int n = offs[p + 1] - offs[p];
        for (int j = threadIdx.x; j < n; j += 256) s[offs[p] + j] = srcs[p][j];
    }
    __syncthreads();

    int i = blockIdx.x * 256 + threadIdx.x;
    if (i >= NLUT) return;

    const float* sW_fm = s + 0;   const float* sb_fm = s + 128;
    const float* sW_c1 = s + 144; const float* sb_c1 = s + 400;
    const float* sW_p1 = s + 416; const float* sb_p1 = s + 608;
    const float* sW_c2 = s + 620; const float* sb_c2 = s + 716;
    const float* sW_p2 = s + 724; const float* sb_p2 = s + 756;
    const float* sW_c3 = s + 760; const float* sb_c3 = s + 776;
    const float* sW_h  = s + 780; const float* sb_h  = s + 784;

    const float step = 1.0f / (float)(NLUT - 1);
    float x0 = (float)i * step;
    float x1 = fminf((float)(i + 1) * step, 1.0f);
    float f0 = eval_net(x0, sW_fm, sb_fm, sW_c1, sb_c1, sW_p1, sb_p1,
                        sW_c2, sb_c2, sW_p2, sb_p2, sW_c3, sb_c3, sW_h, sb_h);
    float f1 = eval_net(x1, sW_fm, sb_fm, sW_c1, sb_c1, sW_p1, sb_p1,
                        sW_c2, sb_c2, sW_p2, sb_p2, sW_c3, sb_c3, sW_h, sb_h);
    lut[i] = make_float2(f0, f1 - f0);
}

// ---------------------------------------------------------------------------
// Kernel 2: memory-bound streaming pass. 1024 samples per 256-thread block.
// ---------------------------------------------------------------------------
__global__ __launch_bounds__(256) void qcnn_main_kernel(
    const float4* __restrict__ data,
    const float* __restrict__ conv_w, const float* __restrict__ conv_b,
    const float2* __restrict__ lut, float* __restrict__ out, int n)
{
    __shared__ float2 slut[NLUT];
    for (int i = threadIdx.x; i < NLUT; i += 256) slut[i] = lut[i];
    const float w0 = conv_w[0], w1 = conv_w[1], w2 = conv_w[2], w3 = conv_w[3];
    const float cb = conv_b[0];
    __syncthreads();

    int base = blockIdx.x * 1024 + threadIdx.x;
    #pragma unroll
    for (int k = 0; k < 4; ++k) {
        int sidx = base + k * 256;
        if (sidx < n) {
            float4 d = data[sidx];
            float logit = fmaf(d.x, w0, fmaf(d.y, w1,
                          fmaf(d.z, w2, fmaf(d.w, w3, cb))));
            float cv = __fdividef(1.0f, 1.0f + __expf(-logit));
            float t = cv * (float)(NLUT - 1);
            int idx = (int)t;
            idx = idx < (NLUT - 1) ? idx : (NLUT - 1);
            idx = idx > 0 ? idx : 0;
            float fr = t - (float)idx;
            float2 v = slut[idx];
            out[sidx] = fmaf(fr, v.y, v.x);
        }
    }
}

// ---------------------------------------------------------------------------
// Fallback (only if d_ws is too small for the LUT): direct per-sample eval.
// ---------------------------------------------------------------------------
__global__ __launch_bounds__(256) void qcnn_direct_kernel(
    const float4* __restrict__ data,
    const float* __restrict__ conv_w, const float* __restrict__ conv_b,
    const float* W_fm, const float* b_fm, const float* W_c1, const float* b_c1,
    const float* W_p1, const float* b_p1, const float* W_c2, const float* b_c2,
    const float* W_p2, const float* b_p2, const float* W_c3, const float* b_c3,
    const float* W_h,  const float* b_h,
    float* __restrict__ out, int n)
{
    int sidx = blockIdx.x * 256 + threadIdx.x;
    if (sidx >= n) return;
    float4 d = data[sidx];
    float logit = fmaf(d.x, conv_w[0], fmaf(d.y, conv_w[1],
                  fmaf(d.z, conv_w[2], fmaf(d.w, conv_w[3], conv_b[0]))));
    float cv = 1.0f / (1.0f + expf(-logit));
    out[sidx] = eval_net(cv, W_fm, b_fm, W_c1, b_c1, W_p1, b_p1,
                         W_c2, b_c2, W_p2, b_p2, W_c3, b_c3, W_h, b_h);
}

extern "C" void kernel_launch(void* const* d_in, const int* in_sizes, int n_in,
                              void* d_out, int out_size, void* d_ws, size_t ws_size,
                              hipStream_t stream) {
    const float* data   = (const float*)d_in[0];
    const float* conv_w = (const float*)d_in[1];
    const float* conv_b = (const float*)d_in[2];
    const float* W_fm = (const float*)d_in[3];  const float* b_fm = (const float*)d_in[4];
    const float* W_c1 = (const float*)d_in[5];  const float* b_c1 = (const float*)d_in[6];
    const float* W_p1 = (const float*)d_in[7];  const float* b_p1 = (const float*)d_in[8];
    const float* W_c2 = (const float*)d_in[9];  const float* b_c2 = (const float*)d_in[10];
    const float* W_p2 = (const float*)d_in[11]; const float* b_p2 = (const float*)d_in[12];
    const float* W_c3 = (const float*)d_in[13]; const float* b_c3 = (const float*)d_in[14];
    const float* W_h  = (const float*)d_in[15]; const float* b_h  = (const float*)d_in[16];
    float* out = (float*)d_out;
    const int B = in_sizes[0] / 4;  // samples; data is B x (1,2,2) = B float4s

    if (ws_size >= NLUT * sizeof(float2)) {
        float2* lut = (float2*)d_ws;
        build_lut_kernel<<<(NLUT + 255) / 256, 256, 0, stream>>>(
            W_fm, b_fm, W_c1, b_c1, W_p1, b_p1, W_c2, b_c2,
            W_p2, b_p2, W_c3, b_c3, W_h, b_h, lut);
        int blocks = (B + 1023) / 1024;
        qcnn_main_kernel<<<blocks, 256, 0, stream>>>(
            (const float4*)data, conv_w, conv_b, lut, out, B);
    } else {
        int blocks = (B + 255) / 256;
        qcnn_direct_kernel<<<blocks, 256, 0, stream>>>(
            (const float4*)data, conv_w, conv_b,
            W_fm, b_fm, W_c1, b_c1, W_p1, b_p1, W_c2, b_c2,
            W_p2, b_p2, W_c3, b_c3, W_h, b_h, out, B);
    }
}

// Round 2
// 139.978 us; speedup vs baseline: 1.5629x; 1.5629x over previous
//
#include <hip/hip_runtime.h>
#include <math.h>

#define NLUT 2048   // intervals; nodes = NLUT+1

// Fast tanh via hardware exp: tanh(x) = (e^2x - 1)/(e^2x + 1). ~1e-7 rel err.
__device__ __forceinline__ float fast_tanh(float x) {
    float e = __expf(2.0f * x);
    return __fdividef(e - 1.0f, e + 1.0f);
}

// ---------------------------------------------------------------------------
// Full QCNN evaluation for one scalar input x (the broadcast conv_val).
// Layers: 8->16->16->12->8->4->4->1. Weight pointers point into LDS.
// ---------------------------------------------------------------------------
__device__ __forceinline__ float eval_net(
    float x,
    const float* W_fm, const float* b_fm,
    const float* W_c1, const float* b_c1,
    const float* W_p1, const float* b_p1,
    const float* W_c2, const float* b_c2,
    const float* W_p2, const float* b_p2,
    const float* W_c3, const float* b_c3,
    const float* W_h,  const float* b_h)
{
    float h[16], g[16];
    #pragma unroll
    for (int j = 0; j < 16; ++j) {
        float a = b_fm[j];
        #pragma unroll
        for (int i = 0; i < 8; ++i) a = fmaf(x, W_fm[i * 16 + j], a);
        h[j] = fast_tanh(a);
    }
    #pragma unroll
    for (int j = 0; j < 16; ++j) {
        float a = b_c1[j];
        #pragma unroll
        for (int i = 0; i < 16; ++i) a = fmaf(h[i], W_c1[i * 16 + j], a);
        g[j] = fast_tanh(a);
    }
    #pragma unroll
    for (int j = 0; j < 12; ++j) {
        float a = b_p1[j];
        #pragma unroll
        for (int i = 0; i < 16; ++i) a = fmaf(g[i], W_p1[i * 12 + j], a);
        h[j] = fast_tanh(a);
    }
    #pragma unroll
    for (int j = 0; j < 8; ++j) {
        float a = b_c2[j];
        #pragma unroll
        for (int i = 0; i < 12; ++i) a = fmaf(h[i], W_c2[i * 8 + j], a);
        g[j] = fast_tanh(a);
    }
    #pragma unroll
    for (int j = 0; j < 4; ++j) {
        float a = b_p2[j];
        #pragma unroll
        for (int i = 0; i < 8; ++i) a = fmaf(g[i], W_p2[i * 4 + j], a);
        h[j] = fast_tanh(a);
    }
    #pragma unroll
    for (int j = 0; j < 4; ++j) {
        float a = b_c3[j];
        #pragma unroll
        for (int i = 0; i < 4; ++i) a = fmaf(h[i], W_c3[i * 4 + j], a);
        g[j] = fast_tanh(a);
    }
    float a = b_h[0];
    #pragma unroll
    for (int i = 0; i < 4; ++i) a = fmaf(g[i], W_h[i], a);
    return __fdividef(1.0f, 1.0f + __expf(-a));
}

// ---------------------------------------------------------------------------
// Kernel 1: build LUT node values f(i/NLUT), i = 0..NLUT  (NLUT+1 evals,
// one per thread — adjacent nodes shared by main-kernel interpolation).
// ---------------------------------------------------------------------------
__global__ __launch_bounds__(256) void build_lut_kernel(
    const float* __restrict__ W_fm, const float* __restrict__ b_fm,
    const float* __restrict__ W_c1, const float* __restrict__ b_c1,
    const float* __restrict__ W_p1, const float* __restrict__ b_p1,
    const float* __restrict__ W_c2, const float* __restrict__ b_c2,
    const float* __restrict__ W_p2, const float* __restrict__ b_p2,
    const float* __restrict__ W_c3, const float* __restrict__ b_c3,
    const float* __restrict__ W_h,  const float* __restrict__ b_h,
    float* __restrict__ lut)
{
    __shared__ float s[785];
    for (int j = threadIdx.x; j < 128; j += 256) s[j]       = W_fm[j];
    if (threadIdx.x < 16)                        s[128 + threadIdx.x] = b_fm[threadIdx.x];
    for (int j = threadIdx.x; j < 256; j += 256) s[144 + j] = W_c1[j];
    if (threadIdx.x < 16)                        s[400 + threadIdx.x] = b_c1[threadIdx.x];
    for (int j = threadIdx.x; j < 192; j += 256) s[416 + j] = W_p1[j];
    if (threadIdx.x < 12)                        s[608 + threadIdx.x] = b_p1[threadIdx.x];
    for (int j = threadIdx.x; j < 96;  j += 256) s[620 + j] = W_c2[j];
    if (threadIdx.x < 8)                         s[716 + threadIdx.x] = b_c2[threadIdx.x];
    for (int j = threadIdx.x; j < 32;  j += 256) s[724 + j] = W_p2[j];
    if (threadIdx.x < 4)                         s[756 + threadIdx.x] = b_p2[threadIdx.x];
    for (int j = threadIdx.x; j < 16;  j += 256) s[760 + j] = W_c3[j];
    if (threadIdx.x < 4)                         s[776 + threadIdx.x] = b_c3[threadIdx.x];
    if (threadIdx.x < 4)                         s[780 + threadIdx.x] = W_h[threadIdx.x];
    if (threadIdx.x == 0)                        s[784] = b_h[0];
    __syncthreads();

    int i = blockIdx.x * 256 + threadIdx.x;
    if (i > NLUT) return;

    float x = (float)i * (1.0f / (float)NLUT);
    lut[i] = eval_net(x,
                      s + 0,   s + 128, s + 144, s + 400, s + 416, s + 608,
                      s + 620, s + 716, s + 724, s + 756, s + 760, s + 776,
                      s + 780, s + 784);
}

// ---------------------------------------------------------------------------
// Kernel 2: memory-bound streaming pass. 1024 samples per 256-thread block.
// ---------------------------------------------------------------------------
__global__ __launch_bounds__(256) void qcnn_main_kernel(
    const float4* __restrict__ data,
    const float* __restrict__ conv_w, const float* __restrict__ conv_b,
    const float* __restrict__ lut, float* __restrict__ out, int n)
{
    __shared__ float slut[NLUT + 1];
    for (int i = threadIdx.x; i <= NLUT; i += 256) slut[i] = lut[i];
    const float w0 = conv_w[0], w1 = conv_w[1], w2 = conv_w[2], w3 = conv_w[3];
    const float cb = conv_b[0];
    __syncthreads();

    int base = blockIdx.x * 1024 + threadIdx.x;
    #pragma unroll
    for (int k = 0; k < 4; ++k) {
        int sidx = base + k * 256;
        if (sidx < n) {
            float4 d = data[sidx];
            float logit = fmaf(d.x, w0, fmaf(d.y, w1,
                          fmaf(d.z, w2, fmaf(d.w, w3, cb))));
            float cv = __fdividef(1.0f, 1.0f + __expf(-logit));
            float t = cv * (float)NLUT;          // in [0, NLUT]
            int idx = (int)t;
            idx = idx < NLUT ? idx : (NLUT - 1);
            idx = idx > 0 ? idx : 0;
            float fr = t - (float)idx;
            float v0 = slut[idx];
            float v1 = slut[idx + 1];
            out[sidx] = fmaf(fr, v1 - v0, v0);
        }
    }
}

extern "C" void kernel_launch(void* const* d_in, const int* in_sizes, int n_in,
                              void* d_out, int out_size, void* d_ws, size_t ws_size,
                              hipStream_t stream) {
    const float* data   = (const float*)d_in[0];
    const float* conv_w = (const float*)d_in[1];
    const float* conv_b = (const float*)d_in[2];
    const float* W_fm = (const float*)d_in[3];  const float* b_fm = (const float*)d_in[4];
    const float* W_c1 = (const float*)d_in[5];  const float* b_c1 = (const float*)d_in[6];
    const float* W_p1 = (const float*)d_in[7];  const float* b_p1 = (const float*)d_in[8];
    const float* W_c2 = (const float*)d_in[9];  const float* b_c2 = (const float*)d_in[10];
    const float* W_p2 = (const float*)d_in[11]; const float* b_p2 = (const float*)d_in[12];
    const float* W_c3 = (const float*)d_in[13]; const float* b_c3 = (const float*)d_in[14];
    const float* W_h  = (const float*)d_in[15]; const float* b_h  = (const float*)d_in[16];
    float* out = (float*)d_out;
    const int B = in_sizes[0] / 4;  // samples; data is B x (1,2,2) = B float4s

    float* lut = (float*)d_ws;      // needs (NLUT+1)*4 = 8196 bytes
    build_lut_kernel<<<(NLUT + 1 + 255) / 256, 256, 0, stream>>>(
        W_fm, b_fm, W_c1, b_c1, W_p1, b_p1, W_c2, b_c2,
        W_p2, b_p2, W_c3, b_c3, W_h, b_h, lut);
    int blocks = (B + 1023) / 1024;
    qcnn_main_kernel<<<blocks, 256, 0, stream>>>(
        (const float4*)data, conv_w, conv_b, lut, out, B);
}

// Round 3
// 138.188 us; speedup vs baseline: 1.5832x; 1.0129x over previous
//
#include <hip/hip_runtime.h>
#include <math.h>

#define NLUT 2048   // intervals; nodes = NLUT+1 (8196 B table, fits in 32 KB L1)

// Fast tanh via hardware exp: tanh(x) = (e^2x - 1)/(e^2x + 1). ~1e-7 rel err.
__device__ __forceinline__ float fast_tanh(float x) {
    float e = __expf(2.0f * x);
    return __fdividef(e - 1.0f, e + 1.0f);
}

// ---------------------------------------------------------------------------
// Full QCNN evaluation for one scalar input x (the broadcast conv_val).
// Layers: 8->16->16->12->8->4->4->1. Weight pointers point into LDS.
// ---------------------------------------------------------------------------
__device__ __forceinline__ float eval_net(
    float x,
    const float* W_fm, const float* b_fm,
    const float* W_c1, const float* b_c1,
    const float* W_p1, const float* b_p1,
    const float* W_c2, const float* b_c2,
    const float* W_p2, const float* b_p2,
    const float* W_c3, const float* b_c3,
    const float* W_h,  const float* b_h)
{
    float h[16], g[16];
    #pragma unroll
    for (int j = 0; j < 16; ++j) {
        float a = b_fm[j];
        #pragma unroll
        for (int i = 0; i < 8; ++i) a = fmaf(x, W_fm[i * 16 + j], a);
        h[j] = fast_tanh(a);
    }
    #pragma unroll
    for (int j = 0; j < 16; ++j) {
        float a = b_c1[j];
        #pragma unroll
        for (int i = 0; i < 16; ++i) a = fmaf(h[i], W_c1[i * 16 + j], a);
        g[j] = fast_tanh(a);
    }
    #pragma unroll
    for (int j = 0; j < 12; ++j) {
        float a = b_p1[j];
        #pragma unroll
        for (int i = 0; i < 16; ++i) a = fmaf(g[i], W_p1[i * 12 + j], a);
        h[j] = fast_tanh(a);
    }
    #pragma unroll
    for (int j = 0; j < 8; ++j) {
        float a = b_c2[j];
        #pragma unroll
        for (int i = 0; i < 12; ++i) a = fmaf(h[i], W_c2[i * 8 + j], a);
        g[j] = fast_tanh(a);
    }
    #pragma unroll
    for (int j = 0; j < 4; ++j) {
        float a = b_p2[j];
        #pragma unroll
        for (int i = 0; i < 8; ++i) a = fmaf(g[i], W_p2[i * 4 + j], a);
        h[j] = fast_tanh(a);
    }
    #pragma unroll
    for (int j = 0; j < 4; ++j) {
        float a = b_c3[j];
        #pragma unroll
        for (int i = 0; i < 4; ++i) a = fmaf(h[i], W_c3[i * 4 + j], a);
        g[j] = fast_tanh(a);
    }
    float a = b_h[0];
    #pragma unroll
    for (int i = 0; i < 4; ++i) a = fmaf(g[i], W_h[i], a);
    return __fdividef(1.0f, 1.0f + __expf(-a));
}

// ---------------------------------------------------------------------------
// Kernel 1: build LUT node values f(i/NLUT), i = 0..NLUT (one eval/thread).
// ---------------------------------------------------------------------------
__global__ __launch_bounds__(256) void build_lut_kernel(
    const float* __restrict__ W_fm, const float* __restrict__ b_fm,
    const float* __restrict__ W_c1, const float* __restrict__ b_c1,
    const float* __restrict__ W_p1, const float* __restrict__ b_p1,
    const float* __restrict__ W_c2, const float* __restrict__ b_c2,
    const float* __restrict__ W_p2, const float* __restrict__ b_p2,
    const float* __restrict__ W_c3, const float* __restrict__ b_c3,
    const float* __restrict__ W_h,  const float* __restrict__ b_h,
    float* __restrict__ lut)
{
    __shared__ float s[785];
    for (int j = threadIdx.x; j < 128; j += 256) s[j]       = W_fm[j];
    if (threadIdx.x < 16)                        s[128 + threadIdx.x] = b_fm[threadIdx.x];
    for (int j = threadIdx.x; j < 256; j += 256) s[144 + j] = W_c1[j];
    if (threadIdx.x < 16)                        s[400 + threadIdx.x] = b_c1[threadIdx.x];
    for (int j = threadIdx.x; j < 192; j += 256) s[416 + j] = W_p1[j];
    if (threadIdx.x < 12)                        s[608 + threadIdx.x] = b_p1[threadIdx.x];
    for (int j = threadIdx.x; j < 96;  j += 256) s[620 + j] = W_c2[j];
    if (threadIdx.x < 8)                         s[716 + threadIdx.x] = b_c2[threadIdx.x];
    for (int j = threadIdx.x; j < 32;  j += 256) s[724 + j] = W_p2[j];
    if (threadIdx.x < 4)                         s[756 + threadIdx.x] = b_p2[threadIdx.x];
    for (int j = threadIdx.x; j < 16;  j += 256) s[760 + j] = W_c3[j];
    if (threadIdx.x < 4)                         s[776 + threadIdx.x] = b_c3[threadIdx.x];
    if (threadIdx.x < 4)                         s[780 + threadIdx.x] = W_h[threadIdx.x];
    if (threadIdx.x == 0)                        s[784] = b_h[0];
    __syncthreads();

    int i = blockIdx.x * 256 + threadIdx.x;
    if (i > NLUT) return;

    float x = (float)i * (1.0f / (float)NLUT);
    lut[i] = eval_net(x,
                      s + 0,   s + 128, s + 144, s + 400, s + 416, s + 608,
                      s + 620, s + 716, s + 724, s + 756, s + 760, s + 776,
                      s + 780, s + 784);
}

// ---------------------------------------------------------------------------
// Kernel 2: pure streaming pass. No LDS, no barrier; the 8 KB LUT is read
// directly from global (fully L1-resident per CU after warmup).
// ---------------------------------------------------------------------------
__global__ __launch_bounds__(256) void qcnn_main_kernel(
    const float4* __restrict__ data,
    const float* __restrict__ conv_w, const float* __restrict__ conv_b,
    const float* __restrict__ lut, float* __restrict__ out, int n)
{
    const float w0 = conv_w[0], w1 = conv_w[1], w2 = conv_w[2], w3 = conv_w[3];
    const float cb = conv_b[0];

    int tid = blockIdx.x * 256 + threadIdx.x;
    int stride = gridDim.x * 256;
    for (int sidx = tid; sidx < n; sidx += stride) {
        float4 d = data[sidx];
        float logit = fmaf(d.x, w0, fmaf(d.y, w1,
                      fmaf(d.z, w2, fmaf(d.w, w3, cb))));
        float cv = __fdividef(1.0f, 1.0f + __expf(-logit));
        float t = cv * (float)NLUT;          // in [0, NLUT]
        int idx = (int)t;
        idx = idx < NLUT ? idx : (NLUT - 1);
        idx = idx > 0 ? idx : 0;
        float fr = t - (float)idx;
        float v0 = lut[idx];
        float v1 = lut[idx + 1];
        out[sidx] = fmaf(fr, v1 - v0, v0);
    }
}

extern "C" void kernel_launch(void* const* d_in, const int* in_sizes, int n_in,
                              void* d_out, int out_size, void* d_ws, size_t ws_size,
                              hipStream_t stream) {
    const float* data   = (const float*)d_in[0];
    const float* conv_w = (const float*)d_in[1];
    const float* conv_b = (const float*)d_in[2];
    const float* W_fm = (const float*)d_in[3];  const float* b_fm = (const float*)d_in[4];
    const float* W_c1 = (const float*)d_in[5];  const float* b_c1 = (const float*)d_in[6];
    const float* W_p1 = (const float*)d_in[7];  const float* b_p1 = (const float*)d_in[8];
    const float* W_c2 = (const float*)d_in[9];  const float* b_c2 = (const float*)d_in[10];
    const float* W_p2 = (const float*)d_in[11]; const float* b_p2 = (const float*)d_in[12];
    const float* W_c3 = (const float*)d_in[13]; const float* b_c3 = (const float*)d_in[14];
    const float* W_h  = (const float*)d_in[15]; const float* b_h  = (const float*)d_in[16];
    float* out = (float*)d_out;
    const int B = in_sizes[0] / 4;  // samples; data is B x (1,2,2) = B float4s

    float* lut = (float*)d_ws;      // needs (NLUT+1)*4 = 8196 bytes
    build_lut_kernel<<<(NLUT + 1 + 255) / 256, 256, 0, stream>>>(
        W_fm, b_fm, W_c1, b_c1, W_p1, b_p1, W_c2, b_c2,
        W_p2, b_p2, W_c3, b_c3, W_h, b_h, lut);

    // 4096 blocks x 256 threads, 4 samples/thread via grid-stride.
    qcnn_main_kernel<<<4096, 256, 0, stream>>>(
        (const float4*)data, conv_w, conv_b, lut, out, B);
}